// Round 3
// baseline (2321.333 us; speedup 1.0000x reference)
//
#include <hip/hip_runtime.h>
#include <cstdint>
#include <cstddef>

// Problem constants
#define SEQL   256
#define NBATCH 64
#define HDIM   512
#define ZDIM   2048   // 4*OUT
#define KDIM   1536   // in_dim

typedef __attribute__((ext_vector_type(8))) short short8;
typedef __attribute__((ext_vector_type(4))) float f32x4;
typedef __attribute__((ext_vector_type(16))) float f32x16;
typedef __attribute__((ext_vector_type(4))) float f4v;

static __device__ __forceinline__ unsigned short f2bf(float f) {
  union { float f; unsigned u; } v; v.f = f;
  unsigned u = v.u;
  unsigned r = (u + 0x7FFFu + ((u >> 16) & 1u)) >> 16;   // RNE
  return (unsigned short)r;
}
static __device__ __forceinline__ float bf2f(unsigned short s) {
  union { unsigned u; float f; } v; v.u = ((unsigned)s) << 16; return v.f;
}
static __device__ __forceinline__ float sigm(float x)  { return 1.f / (1.f + __expf(-x)); }
static __device__ __forceinline__ float tanh_f(float x){ return 1.f - 2.f / (__expf(2.f * x) + 1.f); }

static __device__ __forceinline__ void gl_lds16(const void* g, void* l) {
  __builtin_amdgcn_global_load_lds((const __attribute__((address_space(1))) unsigned int*)g,
                                   (__attribute__((address_space(3))) unsigned int*)l, 16, 0, 0);
}

// ---------------------------------------------------------------- prep kernels

// x (b,t,k) f32 -> Xb[r][k] bf16 with r = t*64 + b
__global__ __launch_bounds__(256) void k_convx(const float* __restrict__ x,
                                               unsigned short* __restrict__ Xb) {
  int i = blockIdx.x * 256 + threadIdx.x;
  int k8 = (i & 63) * 8;
  int r  = i >> 6;
  int b  = r & 63, t = r >> 6;
  const float* src = x + ((size_t)(b * SEQL + t) * HDIM + k8);
  f4v v0 = *(const f4v*)src;
  f4v v1 = *(const f4v*)(src + 4);
  short8 o;
#pragma unroll
  for (int j = 0; j < 4; ++j) o[j] = (short)f2bf(v0[j]);
#pragma unroll
  for (int j = 0; j < 4; ++j) o[4 + j] = (short)f2bf(v1[j]);
  *(short8*)(Xb + (size_t)r * HDIM + k8) = o;
}

// g (64,512) f32 -> bf16
__global__ __launch_bounds__(256) void k_convg(const float* __restrict__ g,
                                               unsigned short* __restrict__ gbf) {
  int i = blockIdx.x * 256 + threadIdx.x;
  int k8 = (i & 63) * 8;
  int row = i >> 6;
  const float* src = g + ((size_t)row * HDIM + k8);
  f4v v0 = *(const f4v*)src;
  f4v v1 = *(const f4v*)(src + 4);
  short8 o;
#pragma unroll
  for (int j = 0; j < 4; ++j) o[j] = (short)f2bf(v0[j]);
#pragma unroll
  for (int j = 0; j < 4; ++j) o[4 + j] = (short)f2bf(v1[j]);
  *(short8*)(gbf + (size_t)row * HDIM + k8) = o;
}

// W (1536,2048) f32 -> Wt (2048,1536) bf16 (transposed)
__global__ __launch_bounds__(256) void k_trans(const float* __restrict__ W,
                                               unsigned short* __restrict__ Wt) {
  __shared__ float tile[32][33];
  int tx = threadIdx.x & 31, ty = threadIdx.x >> 5;
  int n0 = blockIdx.x * 32;
  int j0 = blockIdx.y * 32;
#pragma unroll
  for (int jj = 0; jj < 4; ++jj)
    tile[ty + jj * 8][tx] = W[(size_t)(j0 + ty + jj * 8) * ZDIM + n0 + tx];
  __syncthreads();
#pragma unroll
  for (int jj = 0; jj < 4; ++jj)
    Wt[(size_t)(n0 + ty + jj * 8) * KDIM + j0 + tx] = f2bf(tile[tx][ty + jj * 8]);
}

// gbuf[64][2048] = g @ Wg + bias
__global__ __launch_bounds__(256) void k_gb(const unsigned short* __restrict__ gbf,
                                            const unsigned short* __restrict__ Wt,
                                            const float* __restrict__ bias,
                                            float* __restrict__ gbuf) {
  int tid = threadIdx.x, l = tid & 63, w = tid >> 6;
  int n0 = blockIdx.x * 64 + w * 16;
  f32x4 acc[4] = {};
#pragma unroll
  for (int kb = 0; kb < 16; ++kb) {
    short8 bfr = *(const short8*)((const char*)Wt + (size_t)(n0 + (l & 15)) * 3072
                                  + 2048 + kb * 64 + (l >> 4) * 16);
#pragma unroll
    for (int mi = 0; mi < 4; ++mi) {
      short8 afr = *(const short8*)((const char*)gbf + (size_t)(mi * 16 + (l & 15)) * 1024
                                    + kb * 64 + (l >> 4) * 16);
      acc[mi] = __builtin_amdgcn_mfma_f32_16x16x32_bf16(afr, bfr, acc[mi], 0, 0, 0);
    }
  }
  int r0 = (l >> 4) * 4, cq = l & 15;
#pragma unroll
  for (int mi = 0; mi < 4; ++mi)
#pragma unroll
    for (int reg = 0; reg < 4; ++reg) {
      int row = mi * 16 + r0 + reg, col = n0 + cq;
      gbuf[(size_t)row * ZDIM + col] = acc[mi][reg] + bias[col];
    }
}

// ------------------------------------------------- phase-1 GEMM: zpre = Xb @ Wx^T + gbuf
__global__ __launch_bounds__(256, 2) void k_gemm_p1(const unsigned short* __restrict__ Xb,
                                                    const unsigned short* __restrict__ Wt,
                                                    const float* __restrict__ gbuf,
                                                    unsigned short* __restrict__ zpre) {
  __shared__ unsigned char sm[32768];
  int tm = blockIdx.x, tn = blockIdx.y;
  int tid = threadIdx.x, l = tid & 63, w = tid >> 6;
  int m0w = (w & 1) * 64, n0w = (w >> 1) * 64;
  f32x4 acc[4][4] = {};

  for (int k0 = 0; k0 < HDIM; k0 += 64) {
#pragma unroll
    for (int j = 0; j < 8; ++j) {
      int c = j * 4 + w;
      int lane_row = l >> 3;
      int kb = (l & 7) * 16;
      const char* gsrc;
      if (c < 16) {
        int row = c * 8 + lane_row;
        gsrc = (const char*)Xb + (size_t)(tm * 128 + row) * 1024 + k0 * 2 + kb;
      } else {
        int row = (c - 16) * 8 + lane_row;
        gsrc = (const char*)Wt + (size_t)(tn * 128 + row) * 3072 + k0 * 2 + kb;
      }
      gl_lds16(gsrc, (char*)sm + c * 1024);
    }
    __syncthreads();

#pragma unroll
    for (int kk = 0; kk < 64; kk += 32) {
      short8 af[4], bf[4];
#pragma unroll
      for (int mi = 0; mi < 4; ++mi)
        af[mi] = *(const short8*)((const char*)sm + (size_t)(m0w + mi * 16 + (l & 15)) * 128
                                  + (kk + (l >> 4) * 8) * 2);
#pragma unroll
      for (int ni = 0; ni < 4; ++ni)
        bf[ni] = *(const short8*)((const char*)sm + 16384 + (size_t)(n0w + ni * 16 + (l & 15)) * 128
                                  + (kk + (l >> 4) * 8) * 2);
#pragma unroll
      for (int mi = 0; mi < 4; ++mi)
#pragma unroll
        for (int ni = 0; ni < 4; ++ni)
          acc[mi][ni] = __builtin_amdgcn_mfma_f32_16x16x32_bf16(af[mi], bf[ni], acc[mi][ni], 0, 0, 0);
    }
    __syncthreads();
  }

  int r0 = (l >> 4) * 4, cq = l & 15;
#pragma unroll
  for (int mi = 0; mi < 4; ++mi)
#pragma unroll
    for (int ni = 0; ni < 4; ++ni) {
      int col = tn * 128 + n0w + ni * 16 + cq;
#pragma unroll
      for (int reg = 0; reg < 4; ++reg) {
        int row = tm * 128 + m0w + mi * 16 + r0 + reg;
        float v = acc[mi][ni][reg] + gbuf[(size_t)(row & 63) * ZDIM + col];
        zpre[(size_t)row * ZDIM + col] = f2bf(v);
      }
    }
}

// ---------------------------------------------------------- persistent recurrence
// 64 wgs = 2 dir x 2 row-bands(32 rows) x 16 col-groups(32 h-cols = 128 z-cols).
// 4 independent flag-broadcast barriers, one per (dir, band) group of 16 wgs.
// bid layout puts each group on 2 XCDs (bid%8 round-robin assumption, perf-only).

__global__ __launch_bounds__(256, 1) void k_rec(const unsigned short* __restrict__ Wt,
                                                const unsigned short* __restrict__ zpre,
                                                unsigned short* __restrict__ hbuf, // [2][2][64][512] bf16
                                                unsigned* __restrict__ sync_ws,
                                                float* __restrict__ out,
                                                float* __restrict__ hstate,
                                                float* __restrict__ cstate) {
  __shared__ short lwh[128 * 512];    // 128KB: [lc(gate*32+hc)][k] bf16, XOR-swizzled
  __shared__ float zbuf[32][128];     // 16KB

  const int tid = threadIdx.x, l = tid & 63, wv = tid >> 6;
  const int bid = blockIdx.x;
  const int x = bid & 7, grp = x >> 1, cg = ((bid >> 3) << 1) | (x & 1);
  const int dir = grp >> 1, rg = grp & 1;

  // --- stage Wh slice (128 z-cols) into LDS, pre-swizzled source, linear dest
#pragma unroll
  for (int it = 0; it < 32; ++it) {
    int flat = it * 4096 + tid * 16;
    int lc = flat >> 10, kbs = flat & 1023;
    int kbyte = kbs ^ ((lc & 7) << 4);
    int zcol = (lc >> 5) * 512 + cg * 32 + (lc & 31);
    short8 v = *(const short8*)((const char*)Wt + (size_t)zcol * 3072 + 1024 + kbyte);
    *(short8*)((char*)lwh + flat) = v;
  }

  // --- zero-init hbuf buffer 0 for our (dir, band, cols)
  {
    int row = tid >> 3, c4 = (tid & 7) * 4;
    uint2 z2; z2.x = 0; z2.y = 0;
    *(uint2*)((char*)hbuf + (size_t)(0 * 2 + dir) * 65536
              + (size_t)(rg * 32 + row) * 1024 + (size_t)(cg * 32 + c4) * 2) = z2;
  }

  unsigned* flagbase = sync_ws + grp * 256;   // 16 flags x 64B per group
  unsigned e = 1;

  // initial barrier (zero-init + Wt visibility within group)
  __syncthreads();
  if (tid == 0)
    __hip_atomic_store(flagbase + cg * 16, e, __ATOMIC_RELEASE, __HIP_MEMORY_SCOPE_AGENT);
  if (tid < 16) {
    long gd = 0;
    while (__hip_atomic_load(flagbase + tid * 16, __ATOMIC_RELAXED, __HIP_MEMORY_SCOPE_AGENT) < e) {
      __builtin_amdgcn_s_sleep(1);
      if (++gd > (1L << 22)) break;
    }
  }
  __syncthreads();
  if (tid == 0) __builtin_amdgcn_fence(__ATOMIC_ACQUIRE, "agent");
  __syncthreads();
  ++e;

  const int row_gm = tid >> 3, hcb = tid & 7;   // gate-math coords: row 0..31, hc base 0..7
  float cst[4] = {0.f, 0.f, 0.f, 0.f};
  float hst[4] = {0.f, 0.f, 0.f, 0.f};

  // prefetch zpre for first step
  unsigned short zp[16];
  {
    int t0 = dir ? (SEQL - 1) : 0;
    const unsigned short* zb = zpre + ((size_t)t0 * 64 + rg * 32 + row_gm) * ZDIM + cg * 32 + hcb;
#pragma unroll
    for (int p = 0; p < 4; ++p)
#pragma unroll
      for (int gg = 0; gg < 4; ++gg)
        zp[p * 4 + gg] = __builtin_nontemporal_load(zb + gg * 512 + p * 8);
  }

  const int arow = rg * 32 + (l & 31);
  const int kx16 = (l >> 5) * 16;
  const int lcw  = wv * 32 + (l & 31);     // wave wv owns gate wv's 32 cols
  const int swz  = (l & 7) << 4;

  for (int s = 0; s < SEQL; ++s) {
    int t = dir ? (SEQL - 1 - s) : s;
    int rb = s & 1, wb = rb ^ 1;
    const char* hbase = (const char*)hbuf + (size_t)(rb * 2 + dir) * 65536
                        + (size_t)arow * 1024 + kx16;

    // A: 32 ksteps x 16B per lane, all issued up front
    short8 afr[32];
#pragma unroll
    for (int ks = 0; ks < 32; ++ks) afr[ks] = *(const short8*)(hbase + (size_t)ks * 32);

    f32x16 ac0 = {}, ac1 = {};
#pragma unroll
    for (int ks = 0; ks < 32; ks += 2) {
      short8 b0 = *(const short8*)((const char*)lwh + (size_t)lcw * 1024 + ((ks * 32 + kx16) ^ swz));
      short8 b1 = *(const short8*)((const char*)lwh + (size_t)lcw * 1024 + (((ks + 1) * 32 + kx16) ^ swz));
      ac0 = __builtin_amdgcn_mfma_f32_32x32x16_bf16(afr[ks],     b0, ac0, 0, 0, 0);
      ac1 = __builtin_amdgcn_mfma_f32_32x32x16_bf16(afr[ks + 1], b1, ac1, 0, 0, 0);
    }
    ac0 += ac1;

    // C/D layout 32x32: col=l&31, row=(reg&3)+8*(reg>>2)+4*(l>>5)
#pragma unroll
    for (int reg = 0; reg < 16; ++reg)
      zbuf[(reg & 3) + ((reg >> 2) << 3) + ((l >> 5) << 2)][lcw] = ac0[reg];
    __syncthreads();

    // gate math: thread owns (row_gm, hc = hcb + p*8), p=0..3
#pragma unroll
    for (int p = 0; p < 4; ++p) {
      int hc = hcb + p * 8;
      float zi = zbuf[row_gm][hc]       + bf2f(zp[p * 4 + 0]);
      float zf = zbuf[row_gm][32 + hc]  + bf2f(zp[p * 4 + 1]);
      float zo = zbuf[row_gm][64 + hc]  + bf2f(zp[p * 4 + 2]);
      float zu = zbuf[row_gm][96 + hc]  + bf2f(zp[p * 4 + 3]);
      cst[p] = sigm(zf) * cst[p] + sigm(zi) * tanh_f(zu);
      hst[p] = sigm(zo) * tanh_f(cst[p]);
      hbuf[(size_t)(wb * 2 + dir) * 32768 + (size_t)(rg * 32 + row_gm) * 512 + cg * 32 + hc] = f2bf(hst[p]);
    }

    __syncthreads();   // zbuf reads done; all h-stores issued & drained (vmcnt0 per wave)
    if (tid == 0)
      __hip_atomic_store(flagbase + cg * 16, e, __ATOMIC_RELEASE, __HIP_MEMORY_SCOPE_AGENT);

    // out stores (nontemporal, off critical path)
#pragma unroll
    for (int p = 0; p < 4; ++p)
      __builtin_nontemporal_store(hst[p],
        out + ((size_t)(rg * 32 + row_gm) * SEQL + t) * 1024 + dir * 512 + cg * 32 + hcb + p * 8);

    if (s + 1 < SEQL) {
      // prefetch next zpre (overlaps poll)
      int tn = dir ? (SEQL - 2 - s) : (s + 1);
      const unsigned short* zb = zpre + ((size_t)tn * 64 + rg * 32 + row_gm) * ZDIM + cg * 32 + hcb;
#pragma unroll
      for (int p = 0; p < 4; ++p)
#pragma unroll
        for (int gg = 0; gg < 4; ++gg)
          zp[p * 4 + gg] = __builtin_nontemporal_load(zb + gg * 512 + p * 8);

      if (tid < 16) {
        long gd = 0;
        while (__hip_atomic_load(flagbase + tid * 16, __ATOMIC_RELAXED, __HIP_MEMORY_SCOPE_AGENT) < e) {
          __builtin_amdgcn_s_sleep(1);
          if (++gd > (1L << 22)) break;
        }
      }
      __syncthreads();
      if (tid == 0) __builtin_amdgcn_fence(__ATOMIC_ACQUIRE, "agent");
      __syncthreads();
    }
    ++e;
  }

  // final states
#pragma unroll
  for (int p = 0; p < 4; ++p) {
    size_t st = (size_t)(rg * 32 + row_gm) * 1024 + dir * 512 + cg * 32 + hcb + p * 8;
    __builtin_nontemporal_store(hst[p], hstate + st);
    __builtin_nontemporal_store(cst[p], cstate + st);
  }
}

// ---------------------------------------------------------------------- launch

extern "C" void kernel_launch(void* const* d_in, const int* in_sizes, int n_in,
                              void* d_out, int out_size, void* d_ws, size_t ws_size,
                              hipStream_t stream) {
  const float* x    = (const float*)d_in[0];
  const float* g    = (const float*)d_in[1];
  const float* W    = (const float*)d_in[2];
  const float* bias = (const float*)d_in[3];
  float* out = (float*)d_out;
  float* hstate = out + (size_t)16777216;            // 64*256*1024
  float* cstate = out + (size_t)16842752;            // + 64*1024

  char* ws = (char*)d_ws;
  unsigned*       sync_ws = (unsigned*)(ws + 0);              // 8KB: 4 groups x 16 flags x 64B
  unsigned short* hbuf = (unsigned short*)(ws + 8192);        // 256KB
  unsigned short* Xb   = (unsigned short*)(ws + 270336);      // 16MB
  unsigned short* Wt   = (unsigned short*)(ws + 17047552);    // 6MB
  unsigned short* gbf  = (unsigned short*)(ws + 23339008);    // 64KB
  float*          gbuf = (float*)(ws + 23404544);             // 512KB
  unsigned short* zpre = (unsigned short*)(ws + 23928832);    // 64MB

  hipMemsetAsync((void*)sync_ws, 0, 8192, stream);

  k_convx<<<4096, 256, 0, stream>>>(x, Xb);
  k_convg<<<16, 256, 0, stream>>>(g, gbf);
  k_trans<<<dim3(64, 48), 256, 0, stream>>>(W, Wt);
  k_gb<<<32, 256, 0, stream>>>(gbf, Wt, bias, gbuf);
  k_gemm_p1<<<dim3(128, 16), 256, 0, stream>>>(Xb, Wt, gbuf, zpre);
  k_rec<<<64, 256, 0, stream>>>(Wt, zpre, hbuf, sync_ws, out, hstate, cstate);
}

// Round 5
// 1393.668 us; speedup vs baseline: 1.6656x; 1.6656x over previous
//
#include <hip/hip_runtime.h>
#include <cstdint>
#include <cstddef>

// Problem constants
#define SEQL   256
#define NBATCH 64
#define HDIM   512
#define ZDIM   2048   // 4*OUT
#define KDIM   1536   // in_dim

typedef __attribute__((ext_vector_type(8))) short short8;
typedef __attribute__((ext_vector_type(4))) float f32x4;
typedef __attribute__((ext_vector_type(2))) float f32x2;
typedef __attribute__((ext_vector_type(4))) float f4v;

static __device__ __forceinline__ unsigned short f2bf(float f) {
  union { float f; unsigned u; } v; v.f = f;
  unsigned u = v.u;
  unsigned r = (u + 0x7FFFu + ((u >> 16) & 1u)) >> 16;   // RNE
  return (unsigned short)r;
}
static __device__ __forceinline__ float bf2f(unsigned short s) {
  union { unsigned u; float f; } v; v.u = ((unsigned)s) << 16; return v.f;
}
static __device__ __forceinline__ float sigm(float x)  { return 1.f / (1.f + __expf(-x)); }
static __device__ __forceinline__ float tanh_f(float x){ return 1.f - 2.f / (__expf(2.f * x) + 1.f); }

static __device__ __forceinline__ void gl_lds16(const void* g, void* l) {
  __builtin_amdgcn_global_load_lds((const __attribute__((address_space(1))) unsigned int*)g,
                                   (__attribute__((address_space(3))) unsigned int*)l, 16, 0, 0);
}

// ---------------------------------------------------------------- prep kernels

// x (b,t,k) f32 -> Xb[r][k] bf16 with r = t*64 + b
__global__ __launch_bounds__(256) void k_convx(const float* __restrict__ x,
                                               unsigned short* __restrict__ Xb) {
  int i = blockIdx.x * 256 + threadIdx.x;
  int k8 = (i & 63) * 8;
  int r  = i >> 6;
  int b  = r & 63, t = r >> 6;
  const float* src = x + ((size_t)(b * SEQL + t) * HDIM + k8);
  f4v v0 = *(const f4v*)src;
  f4v v1 = *(const f4v*)(src + 4);
  short8 o;
#pragma unroll
  for (int j = 0; j < 4; ++j) o[j] = (short)f2bf(v0[j]);
#pragma unroll
  for (int j = 0; j < 4; ++j) o[4 + j] = (short)f2bf(v1[j]);
  *(short8*)(Xb + (size_t)r * HDIM + k8) = o;
}

// g (64,512) f32 -> bf16
__global__ __launch_bounds__(256) void k_convg(const float* __restrict__ g,
                                               unsigned short* __restrict__ gbf) {
  int i = blockIdx.x * 256 + threadIdx.x;
  int k8 = (i & 63) * 8;
  int row = i >> 6;
  const float* src = g + ((size_t)row * HDIM + k8);
  f4v v0 = *(const f4v*)src;
  f4v v1 = *(const f4v*)(src + 4);
  short8 o;
#pragma unroll
  for (int j = 0; j < 4; ++j) o[j] = (short)f2bf(v0[j]);
#pragma unroll
  for (int j = 0; j < 4; ++j) o[4 + j] = (short)f2bf(v1[j]);
  *(short8*)(gbf + (size_t)row * HDIM + k8) = o;
}

// W (1536,2048) f32 -> Wt (2048,1536) bf16 (transposed)
__global__ __launch_bounds__(256) void k_trans(const float* __restrict__ W,
                                               unsigned short* __restrict__ Wt) {
  __shared__ float tile[32][33];
  int tx = threadIdx.x & 31, ty = threadIdx.x >> 5;
  int n0 = blockIdx.x * 32;
  int j0 = blockIdx.y * 32;
#pragma unroll
  for (int jj = 0; jj < 4; ++jj)
    tile[ty + jj * 8][tx] = W[(size_t)(j0 + ty + jj * 8) * ZDIM + n0 + tx];
  __syncthreads();
#pragma unroll
  for (int jj = 0; jj < 4; ++jj)
    Wt[(size_t)(n0 + ty + jj * 8) * KDIM + j0 + tx] = f2bf(tile[tx][ty + jj * 8]);
}

// gbuf[64][2048] = g @ Wg + bias
__global__ __launch_bounds__(256) void k_gb(const unsigned short* __restrict__ gbf,
                                            const unsigned short* __restrict__ Wt,
                                            const float* __restrict__ bias,
                                            float* __restrict__ gbuf) {
  int tid = threadIdx.x, l = tid & 63, w = tid >> 6;
  int n0 = blockIdx.x * 64 + w * 16;
  f32x4 acc[4] = {};
#pragma unroll
  for (int kb = 0; kb < 16; ++kb) {
    short8 bfr = *(const short8*)((const char*)Wt + (size_t)(n0 + (l & 15)) * 3072
                                  + 2048 + kb * 64 + (l >> 4) * 16);
#pragma unroll
    for (int mi = 0; mi < 4; ++mi) {
      short8 afr = *(const short8*)((const char*)gbf + (size_t)(mi * 16 + (l & 15)) * 1024
                                    + kb * 64 + (l >> 4) * 16);
      acc[mi] = __builtin_amdgcn_mfma_f32_16x16x32_bf16(afr, bfr, acc[mi], 0, 0, 0);
    }
  }
  int r0 = (l >> 4) * 4, cq = l & 15;
#pragma unroll
  for (int mi = 0; mi < 4; ++mi)
#pragma unroll
    for (int reg = 0; reg < 4; ++reg) {
      int row = mi * 16 + r0 + reg, col = n0 + cq;
      gbuf[(size_t)row * ZDIM + col] = acc[mi][reg] + bias[col];
    }
}

// ------------------------------------------------- phase-1 GEMM: zpre = Xb @ Wx^T + gbuf
__global__ __launch_bounds__(256, 2) void k_gemm_p1(const unsigned short* __restrict__ Xb,
                                                    const unsigned short* __restrict__ Wt,
                                                    const float* __restrict__ gbuf,
                                                    unsigned short* __restrict__ zpre) {
  __shared__ unsigned char sm[32768];
  int tm = blockIdx.x, tn = blockIdx.y;
  int tid = threadIdx.x, l = tid & 63, w = tid >> 6;
  int m0w = (w & 1) * 64, n0w = (w >> 1) * 64;
  f32x4 acc[4][4] = {};

  for (int k0 = 0; k0 < HDIM; k0 += 64) {
#pragma unroll
    for (int j = 0; j < 8; ++j) {
      int c = j * 4 + w;
      int lane_row = l >> 3;
      int kb = (l & 7) * 16;
      const char* gsrc;
      if (c < 16) {
        int row = c * 8 + lane_row;
        gsrc = (const char*)Xb + (size_t)(tm * 128 + row) * 1024 + k0 * 2 + kb;
      } else {
        int row = (c - 16) * 8 + lane_row;
        gsrc = (const char*)Wt + (size_t)(tn * 128 + row) * 3072 + k0 * 2 + kb;
      }
      gl_lds16(gsrc, (char*)sm + c * 1024);
    }
    __syncthreads();

#pragma unroll
    for (int kk = 0; kk < 64; kk += 32) {
      short8 af[4], bf[4];
#pragma unroll
      for (int mi = 0; mi < 4; ++mi)
        af[mi] = *(const short8*)((const char*)sm + (size_t)(m0w + mi * 16 + (l & 15)) * 128
                                  + (kk + (l >> 4) * 8) * 2);
#pragma unroll
      for (int ni = 0; ni < 4; ++ni)
        bf[ni] = *(const short8*)((const char*)sm + 16384 + (size_t)(n0w + ni * 16 + (l & 15)) * 128
                                  + (kk + (l >> 4) * 8) * 2);
#pragma unroll
      for (int mi = 0; mi < 4; ++mi)
#pragma unroll
        for (int ni = 0; ni < 4; ++ni)
          acc[mi][ni] = __builtin_amdgcn_mfma_f32_16x16x32_bf16(af[mi], bf[ni], acc[mi][ni], 0, 0, 0);
    }
    __syncthreads();
  }

  int r0 = (l >> 4) * 4, cq = l & 15;
#pragma unroll
  for (int mi = 0; mi < 4; ++mi)
#pragma unroll
    for (int ni = 0; ni < 4; ++ni) {
      int col = tn * 128 + n0w + ni * 16 + cq;
#pragma unroll
      for (int reg = 0; reg < 4; ++reg) {
        int row = tm * 128 + m0w + mi * 16 + r0 + reg;
        float v = acc[mi][ni][reg] + gbuf[(size_t)(row & 63) * ZDIM + col];
        zpre[(size_t)row * ZDIM + col] = f2bf(v);
      }
    }
}

// ---------------------------------------------------------- persistent recurrence
// 128 wgs = dir(2) x band(4; 16 rows) x colgroup(16; 32 h-cols). 4 waves = 4 gates.
// 8 independent sync groups (dir,band) of 16 wgs; flag-broadcast, NO FENCES:
// h + flags move via L2-bypassing relaxed SYSTEM-scope atomics (coherent at L3/IF).
// __syncthreads() before the flag store drains vmcnt(0) -> h is at the coherence
// point before the flag becomes visible. Readers' bypassing loads cannot hit a
// stale cache, so no acquire is needed. zpre/Wt stay L2-cached (no buffer_inv).

__global__ __launch_bounds__(256, 1) void k_rec(const unsigned short* __restrict__ Wt,
                                                const unsigned short* __restrict__ zpre,
                                                unsigned short* __restrict__ hbuf, // [2][2][4][16][512] bf16
                                                unsigned* __restrict__ sync_ws,
                                                float* __restrict__ out,
                                                float* __restrict__ hstate,
                                                float* __restrict__ cstate) {
  __shared__ short lwh[4 * 32 * 512];   // 128KB: [gate][col(32)][k(512)] bf16, XOR-swizzled
  __shared__ float zbuf[4][16][32];     // 8KB

  const int tid = threadIdx.x, l = tid & 63, gi = tid >> 6;   // wave = gate (i,f,o,u)
  const int bid = blockIdx.x;
  const int cg = bid & 15, gid = bid >> 4, dir = gid >> 2, bg = gid & 3;
  const int hc0 = cg * 32;

  // stage Wh slice (gate gi, cols hc0..hc0+31) into LDS; each wave stages and
  // consumes only its own gate's region -> no barrier needed.
  // content for (col,k): byte col*1024 + (k*2 ^ ((col&7)<<4))
#pragma unroll
  for (int col = 0; col < 32; ++col) {
    int kbs = l * 16;
    int kbyte = kbs ^ ((col & 7) << 4);
    short8 v = *(const short8*)((const char*)Wt
                + (size_t)(gi * 512 + hc0 + col) * 3072 + 1024 + kbyte);
    *(short8*)((char*)lwh + gi * 32768 + col * 1024 + kbs) = v;
  }

  unsigned* fl = sync_ws + gid * 256;   // 16 flags x 64B for this (dir,band) group

  const int r = tid >> 4, q = tid & 15;   // gate-math: row r (0..15), colpair 2q,2q+1
  float c0 = 0.f, c1 = 0.f, h0 = 0.f, h1 = 0.f;

  // prefetch zpre for first step (normal cached loads; L2 stays warm now)
  int t = dir ? (SEQL - 1) : 0;
  unsigned zp[4];
  {
    const char* zb = (const char*)zpre
        + (((size_t)t * 64 + bg * 16 + r) * ZDIM + hc0 + 2 * q) * 2;
#pragma unroll
    for (int gg = 0; gg < 4; ++gg) zp[gg] = *(const unsigned*)(zb + gg * 1024);
  }

  // per-lane h fragment base byte offsets (A of 16x16x32: row=l&15, k-slice by l>>4)
  const int a_off = (l & 15) * 1024 + (l >> 4) * 16;

  for (int s = 0; s < SEQL; ++s) {
    int rb = s & 1, wb = rb ^ 1;
    f32x4 acc0 = {0.f, 0.f, 0.f, 0.f}, acc1 = {0.f, 0.f, 0.f, 0.f};

    if (s) {
      // wait for h(s-1): all 16 col-group flags of this (dir,band) reach s
      if (tid < 16) {
        long gd = 0;
        while (__hip_atomic_load(fl + tid * 16, __ATOMIC_RELAXED,
                                 __HIP_MEMORY_SCOPE_SYSTEM) < (unsigned)s) {
          __builtin_amdgcn_s_sleep(1);
          if (++gd > (1L << 22)) break;   // hang guard
        }
      }
      __syncthreads();

      // A fragments: 16 x 16B via 2x8B L2-bypassing loads (fresh data from L3)
      const char* ha = (const char*)hbuf
          + (((size_t)(rb * 2 + dir)) * 4 + bg) * 16384 + a_off;
      short8 afr[16];
#pragma unroll
      for (int kb = 0; kb < 16; ++kb) {
        union { unsigned long long u[2]; short8 s8; } cv;
        cv.u[0] = __hip_atomic_load((const unsigned long long*)(ha + kb * 64),
                                    __ATOMIC_RELAXED, __HIP_MEMORY_SCOPE_SYSTEM);
        cv.u[1] = __hip_atomic_load((const unsigned long long*)(ha + kb * 64 + 8),
                                    __ATOMIC_RELAXED, __HIP_MEMORY_SCOPE_SYSTEM);
        afr[kb] = cv.s8;
      }

#pragma unroll
      for (int kb = 0; kb < 16; ++kb) {
        int kfrag = kb * 64 + (l >> 4) * 16;
        int kbyte = kfrag ^ ((l & 7) << 4);
        short8 b0 = *(const short8*)((const char*)lwh + gi * 32768 + (size_t)(l & 15) * 1024 + kbyte);
        short8 b1 = *(const short8*)((const char*)lwh + gi * 32768 + (size_t)(16 + (l & 15)) * 1024 + kbyte);
        acc0 = __builtin_amdgcn_mfma_f32_16x16x32_bf16(afr[kb], b0, acc0, 0, 0, 0);
        acc1 = __builtin_amdgcn_mfma_f32_16x16x32_bf16(afr[kb], b1, acc1, 0, 0, 0);
      }
    }
    // s==0: h=0 => Wh contribution is zero; accs stay 0, no sync needed.

    {
      int col = l & 15, row0 = (l >> 4) * 4;
#pragma unroll
      for (int reg = 0; reg < 4; ++reg) {
        zbuf[gi][row0 + reg][col]      = acc0[reg];
        zbuf[gi][row0 + reg][col + 16] = acc1[reg];
      }
    }
    __syncthreads();

    // gate math: thread owns (row r, cols 2q, 2q+1)
    float zi0 = zbuf[0][r][2 * q]     + bf2f((unsigned short)(zp[0] & 0xffffu));
    float zi1 = zbuf[0][r][2 * q + 1] + bf2f((unsigned short)(zp[0] >> 16));
    float zf0 = zbuf[1][r][2 * q]     + bf2f((unsigned short)(zp[1] & 0xffffu));
    float zf1 = zbuf[1][r][2 * q + 1] + bf2f((unsigned short)(zp[1] >> 16));
    float zo0 = zbuf[2][r][2 * q]     + bf2f((unsigned short)(zp[2] & 0xffffu));
    float zo1 = zbuf[2][r][2 * q + 1] + bf2f((unsigned short)(zp[2] >> 16));
    float zu0 = zbuf[3][r][2 * q]     + bf2f((unsigned short)(zp[3] & 0xffffu));
    float zu1 = zbuf[3][r][2 * q + 1] + bf2f((unsigned short)(zp[3] >> 16));

    c0 = sigm(zf0) * c0 + sigm(zi0) * tanh_f(zu0);
    h0 = sigm(zo0) * tanh_f(c0);
    c1 = sigm(zf1) * c1 + sigm(zi1) * tanh_f(zu1);
    h1 = sigm(zo1) * tanh_f(c1);

    // publish h (packed 2xbf16, L2-bypassing store)
    unsigned hp = (unsigned)f2bf(h0) | ((unsigned)f2bf(h1) << 16);
    __hip_atomic_store((unsigned*)((char*)hbuf
        + (((size_t)(wb * 2 + dir)) * 4 + bg) * 16384 + r * 1024 + (hc0 + 2 * q) * 2),
        hp, __ATOMIC_RELAXED, __HIP_MEMORY_SCOPE_SYSTEM);

    __syncthreads();   // drains vmcnt(0) in every wave -> all h stores at L3
    if (tid == 0)
      __hip_atomic_store(fl + cg * 16, (unsigned)(s + 1),
                         __ATOMIC_RELAXED, __HIP_MEMORY_SCOPE_SYSTEM);

    // out store (off critical path, after flag publish)
    {
      f32x2 ho; ho.x = h0; ho.y = h1;
      __builtin_nontemporal_store(ho, reinterpret_cast<f32x2*>(
          out + ((size_t)(bg * 16 + r) * SEQL + t) * 1024 + dir * 512 + hc0 + 2 * q));
    }

    // prefetch next step's zpre (overlaps the next poll)
    if (s + 1 < SEQL) {
      t = dir ? (SEQL - 2 - s) : (s + 1);
      const char* zb = (const char*)zpre
          + (((size_t)t * 64 + bg * 16 + r) * ZDIM + hc0 + 2 * q) * 2;
#pragma unroll
      for (int gg = 0; gg < 4; ++gg) zp[gg] = *(const unsigned*)(zb + gg * 1024);
    }
  }

  // final states
  {
    size_t st = (size_t)(bg * 16 + r) * 1024 + dir * 512 + hc0 + 2 * q;
    f32x2 hv; hv.x = h0; hv.y = h1;
    f32x2 cv2; cv2.x = c0; cv2.y = c1;
    __builtin_nontemporal_store(hv, reinterpret_cast<f32x2*>(hstate + st));
    __builtin_nontemporal_store(cv2, reinterpret_cast<f32x2*>(cstate + st));
  }
}

// ---------------------------------------------------------------------- launch

extern "C" void kernel_launch(void* const* d_in, const int* in_sizes, int n_in,
                              void* d_out, int out_size, void* d_ws, size_t ws_size,
                              hipStream_t stream) {
  const float* x    = (const float*)d_in[0];
  const float* g    = (const float*)d_in[1];
  const float* W    = (const float*)d_in[2];
  const float* bias = (const float*)d_in[3];
  float* out = (float*)d_out;
  float* hstate = out + (size_t)16777216;            // 64*256*1024
  float* cstate = out + (size_t)16842752;            // + 64*1024

  char* ws = (char*)d_ws;
  unsigned*       sync_ws = (unsigned*)(ws + 0);              // 8KB: 8 groups x 16 flags x 64B
  unsigned short* hbuf = (unsigned short*)(ws + 8192);        // 256KB [2][2][4][16][512]
  unsigned short* Xb   = (unsigned short*)(ws + 270336);      // 16MB
  unsigned short* Wt   = (unsigned short*)(ws + 17047552);    // 6MB
  unsigned short* gbf  = (unsigned short*)(ws + 23339008);    // 64KB
  float*          gbuf = (float*)(ws + 23404544);             // 512KB
  unsigned short* zpre = (unsigned short*)(ws + 23928832);    // 64MB

  hipMemsetAsync((void*)sync_ws, 0, 8192, stream);

  k_convx<<<4096, 256, 0, stream>>>(x, Xb);
  k_convg<<<16, 256, 0, stream>>>(g, gbf);
  k_trans<<<dim3(64, 48), 256, 0, stream>>>(W, Wt);
  k_gb<<<32, 256, 0, stream>>>(gbf, Wt, bias, gbuf);
  k_gemm_p1<<<dim3(128, 16), 256, 0, stream>>>(Xb, Wt, gbuf, zpre);
  k_rec<<<128, 256, 0, stream>>>(Wt, zpre, hbuf, sync_ws, out, hstate, cstate);
}